// Round 7
// baseline (1128.174 us; speedup 1.0000x reference)
//
#include <hip/hip_runtime.h>
#include <hip/hip_bf16.h>
#include <math.h>
#include <stdint.h>

#define DEVINL __device__ __forceinline__

constexpr int BB    = 16;
constexpr int TT    = 50;
constexpr int VV    = 50000;
constexpr int HIDN  = 200;
constexpr int G3    = 600;      // 3*HID
constexpr int NROWS = BB * TT;  // 800
constexpr int KP    = 416;      // K=400 padded to mult of 32
constexpr int MP    = 896;      // 800 padded to mult of 128
constexpr int NP    = 50048;    // 50000 padded to mult of 128
constexpr int NTILES = NP / 128; // 391
constexpr int MTILES = MP / 128; // 7
constexpr int OUTW  = VV + HIDN; // 50200
constexpr int WBLKS = NP / 64;   // 782 wout-transpose blocks

typedef __attribute__((ext_vector_type(4))) float f32x4;
typedef __attribute__((ext_vector_type(8))) short bf16x8;

DEVINL unsigned short f2bf(float v) {
    __hip_bfloat16 b = __float2bfloat16(v);
    return *reinterpret_cast<unsigned short*>(&b);
}
DEVINL float bflo(unsigned u) { return __uint_as_float(u << 16); }
DEVINL float bfhi(unsigned u) { return __uint_as_float(u & 0xffff0000u); }

DEVINL void gl_lds16(const void* g, void* lds) {
    __builtin_amdgcn_global_load_lds((const __attribute__((address_space(1))) void*)g,
                                     (__attribute__((address_space(3))) void*)lds,
                                     16, 0, 0);
}

// ---------------------------------------------------------------- W_attn^T
__global__ void __launch_bounds__(256) k_wattnT(const float* __restrict__ W,
                                                float* __restrict__ WT) {
    int i = blockIdx.x * 256 + threadIdx.x;
    if (i < 200 * 200) {
        int k = i / 200, n = i - k * 200;
        WT[(size_t)n * 200 + k] = W[i];
    }
}

// ------------------------------------------- small fp32 GEMM: C = A @ B^T + bias
template <int MODE>
__global__ void __launch_bounds__(256) k_small_gemm(const float* __restrict__ A,
                                                    const float* __restrict__ Brows,
                                                    const float* __restrict__ bias,
                                                    float* __restrict__ C,
                                                    const int* __restrict__ yidx,
                                                    int M, int N) {
    __shared__ float Ash[32][200];
    __shared__ float Bsh[32][200];
    int m0 = blockIdx.x * 32, n0 = blockIdx.y * 32;
    int tid = threadIdx.x;
    for (int i = tid; i < 32 * 200; i += 256) {
        int r = i / 200, k = i - r * 200;
        int gm = m0 + r;
        const float* src;
        if (MODE == 0)      src = A + (size_t)gm * 200;
        else if (MODE == 1) src = A + (size_t)yidx[gm] * 200;
        else { int bb = gm / 200, ss = gm - bb * 200; src = A + ((size_t)bb * 201 + ss) * 200; }
        Ash[r][k] = src[k];
    }
    for (int i = tid; i < 32 * 200; i += 256) {
        int r = i / 200, k = i - r * 200;
        int gn = n0 + r;
        Bsh[r][k] = (gn < N) ? Brows[(size_t)gn * 200 + k] : 0.f;
    }
    __syncthreads();
    int tx = tid & 15, ty = tid >> 4;
    float acc00 = 0, acc01 = 0, acc10 = 0, acc11 = 0;
    #pragma unroll 4
    for (int k = 0; k < 200; ++k) {
        float a0 = Ash[ty][k], a1 = Ash[ty + 16][k];
        float b0 = Bsh[tx][k], b1 = Bsh[tx + 16][k];
        acc00 += a0 * b0; acc01 += a0 * b1;
        acc10 += a1 * b0; acc11 += a1 * b1;
    }
    int gm0 = m0 + ty, gm1 = m0 + ty + 16;
    int gn0 = n0 + tx, gn1 = n0 + tx + 16;
    if (gn0 < N) { C[(size_t)gm0 * N + gn0] = acc00 + bias[gn0];
                   C[(size_t)gm1 * N + gn0] = acc10 + bias[gn0]; }
    if (gn1 < N) { C[(size_t)gm0 * N + gn1] = acc01 + bias[gn1];
                   C[(size_t)gm1 * N + gn1] = acc11 + bias[gn1]; }
}

// ---------------------------------------------------------------- fused GRU + W_out transpose
// LDS is a UNION: GRU uses 76 KB (wlds/hsh/pre/bsh), wout uses 54.4 KB tile.
// -> 2 blocks/CU (vs 1 before). Wout path: 13 independent float4 loads batched
// into regs (one amortized HBM latency), uint4 packed stores.
__global__ void __launch_bounds__(512, 4) k_gru_wout(const float* __restrict__ gi,
                                                     const float* __restrict__ W_hh,
                                                     const float* __restrict__ b_hh,
                                                     const float* __restrict__ h1,
                                                     float* __restrict__ h2,
                                                     const float* __restrict__ W_out,
                                                     unsigned short* __restrict__ WT) {
    __shared__ __align__(16) char smem[76000];
    const int t = threadIdx.x;

    if (blockIdx.x >= BB) {
        // ---------------- W_out transpose path: [400][VV] f32 -> [NP][KP] bf16
        unsigned short (*tile)[68] = reinterpret_cast<unsigned short(*)[68]>(smem); // 54.4 KB
        const int n0 = (blockIdx.x - BB) * 64;
        const int f4 = t & 15, krow = t >> 4;      // 16 col-groups x 32 rows
        const int c0 = f4 * 4;
        const int gn = n0 + c0;
        const int nit = (krow < 16) ? 13 : 12;     // wave-uniform (krow uniform mod wave)

        float4 regs[13];
        #pragma unroll
        for (int it = 0; it < 13; ++it) {          // batch-issue independent loads
            if (it < nit) {
                int k = krow + it * 32;
                const float* src = W_out + (size_t)k * VV + gn;
                if (gn + 3 < VV) {
                    regs[it] = *reinterpret_cast<const float4*>(src);
                } else {
                    float4 v;
                    v.x = (gn     < VV) ? src[0] : 0.f;
                    v.y = (gn + 1 < VV) ? src[1] : 0.f;
                    v.z = (gn + 2 < VV) ? src[2] : 0.f;
                    v.w = (gn + 3 < VV) ? src[3] : 0.f;
                    regs[it] = v;
                }
            }
        }
        #pragma unroll
        for (int it = 0; it < 13; ++it) {
            if (it < nit) {
                int k = krow + it * 32;
                float4 v = regs[it];
                uint2 p;
                p.x = (unsigned)f2bf(v.x) | ((unsigned)f2bf(v.y) << 16);
                p.y = (unsigned)f2bf(v.z) | ((unsigned)f2bf(v.w) << 16);
                *reinterpret_cast<uint2*>(&tile[k][c0]) = p;
            }
        }
        __syncthreads();
        // 64 rows x 52 uint4 (8 bf16 each) per row, fully coalesced 16-B stores
        for (int i = t; i < 64 * 52; i += 512) {
            int n = i / 52, q = i - n * 52;
            int k0 = q * 8;
            uint4 v = {0u, 0u, 0u, 0u};
            if (q < 50) {
                v.x = (unsigned)tile[k0    ][n] | ((unsigned)tile[k0 + 1][n] << 16);
                v.y = (unsigned)tile[k0 + 2][n] | ((unsigned)tile[k0 + 3][n] << 16);
                v.z = (unsigned)tile[k0 + 4][n] | ((unsigned)tile[k0 + 5][n] << 16);
                v.w = (unsigned)tile[k0 + 6][n] | ((unsigned)tile[k0 + 7][n] << 16);
            }
            *reinterpret_cast<uint4*>(WT + (size_t)(n0 + n) * KP + k0) = v;
        }
        return;
    }

    // ---------------- GRU path (identical math to round 6) ----------------
    float (*wlds)[200] = reinterpret_cast<float(*)[200]>(smem);          // 70400 B
    float* hsh = reinterpret_cast<float*>(smem + 70400);                 // 800 B
    float* pre = reinterpret_cast<float*>(smem + 71200);                 // 2400 B
    float* bsh = reinterpret_cast<float*>(smem + 73600);                 // 2400 B
    const int b = blockIdx.x;

    uint4 wb[25];   // W_hh row t as packed bf16 (100 VGPR, static indexing)
    {
        const float4* wrow = reinterpret_cast<const float4*>(W_hh + (size_t)t * 200);
        #pragma unroll
        for (int i = 0; i < 25; ++i) {
            float4 a = wrow[2 * i], c = wrow[2 * i + 1];
            wb[i].x = (unsigned)f2bf(a.x) | ((unsigned)f2bf(a.y) << 16);
            wb[i].y = (unsigned)f2bf(a.z) | ((unsigned)f2bf(a.w) << 16);
            wb[i].z = (unsigned)f2bf(c.x) | ((unsigned)f2bf(c.y) << 16);
            wb[i].w = (unsigned)f2bf(c.z) | ((unsigned)f2bf(c.w) << 16);
        }
    }
    for (int i = t; i < 88 * 200; i += 512) {
        int r = i / 200, k = i - r * 200;
        wlds[r][k] = W_hh[(size_t)(512 + r) * 200 + k];
    }
    for (int i = t; i < 600; i += 512) bsh[i] = b_hh[i];
    if (t < 200) hsh[t] = h1[((size_t)b * 201 + 200) * 200 + t];
    __syncthreads();

    const float4* hsh4 = reinterpret_cast<const float4*>(hsh);
    const int lr = t >> 1, lq = t & 1;

    for (int step = 0; step < TT; ++step) {
        float gr = 0.f, gz = 0.f, gn_ = 0.f, hold = 0.f;
        if (t < 200) {
            const float* girow = gi + ((size_t)b * TT + step) * G3 + t;
            gr  = girow[0];
            gz  = girow[200];
            gn_ = girow[400];
            hold = hsh[t];
        }

        float a0 = 0.f, a1 = 0.f, a2 = 0.f, a3 = 0.f;
        #pragma unroll
        for (int i = 0; i < 25; ++i) {
            uint4 w = wb[i];
            float4 h0 = hsh4[2 * i], h1v = hsh4[2 * i + 1];
            a0 += bflo(w.x) * h0.x;  a1 += bfhi(w.x) * h0.y;
            a2 += bflo(w.y) * h0.z;  a3 += bfhi(w.y) * h0.w;
            a0 += bflo(w.z) * h1v.x; a1 += bfhi(w.z) * h1v.y;
            a2 += bflo(w.w) * h1v.z; a3 += bfhi(w.w) * h1v.w;
        }
        pre[t] = (a0 + a1) + (a2 + a3);

        if (t < 176) {
            const float4* wr4 = reinterpret_cast<const float4*>(&wlds[lr][lq * 100]);
            const float4* hh4 = hsh4 + lq * 25;
            float c0 = 0.f, c1 = 0.f, c2 = 0.f, c3 = 0.f;
            #pragma unroll
            for (int i = 0; i < 25; ++i) {
                float4 wvv = wr4[i];
                float4 hv  = hh4[i];
                c0 += wvv.x * hv.x;
                c1 += wvv.y * hv.y;
                c2 += wvv.z * hv.z;
                c3 += wvv.w * hv.w;
            }
            float cc = (c0 + c1) + (c2 + c3);
            cc += __shfl_xor(cc, 1);
            if (lq == 0) pre[512 + lr] = cc;
        }
        __syncthreads();

        if (t < 200) {
            float pr = gr  + pre[t]       + bsh[t];
            float pz = gz  + pre[200 + t] + bsh[200 + t];
            float hn = pre[400 + t] + bsh[400 + t];
            float r = 1.f / (1.f + __expf(-pr));
            float z = 1.f / (1.f + __expf(-pz));
            float n = tanhf(gn_ + r * hn);
            float hnew = (1.f - z) * n + z * hold;
            hsh[t] = hnew;
            h2[((size_t)b * TT + step) * 200 + t] = hnew;
        }
        __syncthreads();
    }
}

// ---------------------------------------------------------------- fused attention + gate
__global__ void __launch_bounds__(256) k_attn(const float* __restrict__ q,
                                              const float* __restrict__ kv,
                                              const float* __restrict__ h2,
                                              const float* __restrict__ W_gate,
                                              const float* __restrict__ b_gate,
                                              float* __restrict__ out,
                                              float* __restrict__ gbuf,
                                              unsigned short* __restrict__ s2b) {
    int row = blockIdx.x;
    int b = row / TT;
    int tid = threadIdx.x;
    __shared__ __align__(16) float qsh[200];
    __shared__ __align__(16) float h2sh[200];
    __shared__ float ash[200];
    __shared__ float csh[200];
    __shared__ float red[8];

    if (tid < 50) {
        reinterpret_cast<float4*>(qsh)[tid]  = reinterpret_cast<const float4*>(q  + (size_t)row * 200)[tid];
        reinterpret_cast<float4*>(h2sh)[tid] = reinterpret_cast<const float4*>(h2 + (size_t)row * 200)[tid];
    }
    __syncthreads();

    const float* kvb = kv + (size_t)b * 200 * 200;
    float dval = -__builtin_inff();
    if (tid < 200) {
        const float4* kr = reinterpret_cast<const float4*>(kvb + (size_t)tid * 200);
        float s = 0.f;
        #pragma unroll 5
        for (int k4 = 0; k4 < 50; ++k4) {
            float4 kvv = kr[k4];
            float4 qv = reinterpret_cast<float4*>(qsh)[k4];
            s += kvv.x * qv.x + kvv.y * qv.y + kvv.z * qv.z + kvv.w * qv.w;
        }
        dval = s * 0.07071067811865475f;  // 1/sqrt(200)
    }
    float m = dval;
    for (int o = 32; o; o >>= 1) m = fmaxf(m, __shfl_xor(m, o));
    if ((tid & 63) == 0) red[tid >> 6] = m;
    __syncthreads();
    m = fmaxf(fmaxf(red[0], red[1]), fmaxf(red[2], red[3]));
    float e = (tid < 200) ? __expf(dval - m) : 0.f;
    float ssum = e;
    for (int o = 32; o; o >>= 1) ssum += __shfl_xor(ssum, o);
    if ((tid & 63) == 0) red[4 + (tid >> 6)] = ssum;
    __syncthreads();
    float Ssum = red[4] + red[5] + red[6] + red[7];
    float logS = logf(Ssum);
    float p1v = dval - m - logS;
    if (tid < 200) ash[tid] = e / Ssum;
    __syncthreads();

    if (tid < 200) {
        float c = 0.f;
        #pragma unroll 4
        for (int s = 0; s < 200; ++s) c += ash[s] * kvb[(size_t)s * 200 + tid];
        csh[tid] = c;
    }
    __syncthreads();

    float gv = 0.f;
    if (tid < 200) gv = h2sh[tid] * W_gate[tid] + csh[tid] * W_gate[200 + tid];
    for (int o = 32; o; o >>= 1) gv += __shfl_xor(gv, o);
    if ((tid & 63) == 0) red[tid >> 6] = gv;
    __syncthreads();
    float g = red[0] + red[1] + red[2] + red[3] + b_gate[0];

    if (tid == 0) gbuf[row] = g;
    if (tid < 200) out[(size_t)row * OUTW + VV + tid] = (1.f - g) * p1v;

    if (tid < 208) {
        int k = tid * 2;
        float v0 = (k < 200) ? h2sh[k] : (k < 400) ? csh[k - 200] : 0.f;
        float v1 = (k + 1 < 200) ? h2sh[k + 1] : (k + 1 < 400) ? csh[k + 1 - 200] : 0.f;
        unsigned int pk = (unsigned int)f2bf(v0) | ((unsigned int)f2bf(v1) << 16);
        reinterpret_cast<unsigned int*>(s2b + (size_t)row * KP)[tid] = pk;
    }
}

// ---------------------------------------------------------------- big bf16 MFMA GEMM
__global__ void __launch_bounds__(256) k_gemm_big(int pass,
        const unsigned short* __restrict__ Ab, const unsigned short* __restrict__ Bb,
        const float* __restrict__ b_out, float2* __restrict__ partials,
        const float* __restrict__ logZs, const float* __restrict__ gbuf,
        float* __restrict__ out) {
    __shared__ __align__(16) unsigned short Ash[128 * 32];
    __shared__ __align__(16) unsigned short Bsh[128 * 32];
    __shared__ float redsh[128][2][2];
    __shared__ float zsh[128], gsh[128];

    const int m0 = blockIdx.x * 128, n0 = blockIdx.y * 128;
    const int tid = threadIdx.x;
    const int lane = tid & 63, wid = tid >> 6;
    const int wr = wid >> 1, wc = wid & 1;
    const int rq = lane >> 4, r15 = lane & 15;

    if (pass == 2 && tid < 128) {
        int gm = m0 + tid;
        zsh[tid] = (gm < NROWS) ? logZs[gm] : 0.f;
        gsh[tid] = (gm < NROWS) ? gbuf[gm] : 0.f;
    }

    const int c2 = tid + 256;
    const unsigned short* a1 = Ab + (size_t)(m0 + (tid >> 2)) * KP + (tid & 3) * 8;
    const unsigned short* a2 = Ab + (size_t)(m0 + (c2 >> 2)) * KP + (c2 & 3) * 8;
    const unsigned short* b1 = Bb + (size_t)(n0 + (tid >> 2)) * KP + (tid & 3) * 8;
    const unsigned short* b2 = Bb + (size_t)(n0 + (c2 >> 2)) * KP + (c2 & 3) * 8;
    unsigned short* ldsA1 = Ash + wid * 512;
    unsigned short* ldsA2 = Ash + wid * 512 + 2048;
    unsigned short* ldsB1 = Bsh + wid * 512;
    unsigned short* ldsB2 = Bsh + wid * 512 + 2048;

    f32x4 zero = {0.f, 0.f, 0.f, 0.f};
    f32x4 acc[4][4];
    #pragma unroll
    for (int i = 0; i < 4; ++i)
        #pragma unroll
        for (int j = 0; j < 4; ++j) acc[i][j] = zero;

    const bf16x8* A8 = reinterpret_cast<const bf16x8*>(Ash);
    const bf16x8* B8 = reinterpret_cast<const bf16x8*>(Bsh);

    for (int kt = 0; kt < KP / 32; ++kt) {
        const int ko = kt * 32;
        gl_lds16(a1 + ko, ldsA1);
        gl_lds16(a2 + ko, ldsA2);
        gl_lds16(b1 + ko, ldsB1);
        gl_lds16(b2 + ko, ldsB2);
        __syncthreads();
        bf16x8 af[4], bfr[4];
        #pragma unroll
        for (int mi = 0; mi < 4; ++mi) af[mi] = A8[(wr * 64 + mi * 16 + r15) * 4 + rq];
        #pragma unroll
        for (int ni = 0; ni < 4; ++ni) bfr[ni] = B8[(wc * 64 + ni * 16 + r15) * 4 + rq];
        #pragma unroll
        for (int mi = 0; mi < 4; ++mi)
            #pragma unroll
            for (int ni = 0; ni < 4; ++ni)
                acc[mi][ni] = __builtin_amdgcn_mfma_f32_16x16x32_bf16(af[mi], bfr[ni], acc[mi][ni], 0, 0, 0);
        __syncthreads();
    }

    float bias[4]; bool nok[4]; int gn[4];
    #pragma unroll
    for (int ni = 0; ni < 4; ++ni) {
        gn[ni] = n0 + wc * 64 + ni * 16 + r15;
        nok[ni] = gn[ni] < VV;
        bias[ni] = nok[ni] ? b_out[gn[ni]] : 0.f;
    }

    if (pass == 1) {
        #pragma unroll
        for (int mi = 0; mi < 4; ++mi) {
            #pragma unroll
            for (int r = 0; r < 4; ++r) {
                float v[4]; float mx = -__builtin_inff();
                #pragma unroll
                for (int ni = 0; ni < 4; ++ni) {
                    v[ni] = nok[ni] ? (acc[mi][ni][r] + bias[ni]) : -__builtin_inff();
                    mx = fmaxf(mx, v[ni]);
                }
                #pragma unroll
                for (int o = 1; o < 16; o <<= 1) mx = fmaxf(mx, __shfl_xor(mx, o));
                float se = 0.f;
                #pragma unroll
                for (int ni = 0; ni < 4; ++ni) se += nok[ni] ? __expf(v[ni] - mx) : 0.f;
                #pragma unroll
                for (int o = 1; o < 16; o <<= 1) se += __shfl_xor(se, o);
                int ml = wr * 64 + mi * 16 + rq * 4 + r;
                if (r15 == 0) { redsh[ml][wc][0] = mx; redsh[ml][wc][1] = se; }
            }
        }
        __syncthreads();
        if (tid < 128) {
            float m1 = redsh[tid][0][0], s1 = redsh[tid][0][1];
            float m2 = redsh[tid][1][0], s2 = redsh[tid][1][1];
            float mm = fmaxf(m1, m2);
            float ss = s1 * __expf(m1 - mm) + s2 * __expf(m2 - mm);
            partials[(size_t)(m0 + tid) * NTILES + blockIdx.y] = float2{mm, ss};
        }
    } else {
        #pragma unroll
        for (int mi = 0; mi < 4; ++mi) {
            #pragma unroll
            for (int r = 0; r < 4; ++r) {
                int ml = wr * 64 + mi * 16 + rq * 4 + r;
                int gm = m0 + ml;
                if (gm < NROWS) {
                    float gz = gsh[ml], lz = zsh[ml];
                    #pragma unroll
                    for (int ni = 0; ni < 4; ++ni)
                        if (nok[ni])
                            out[(size_t)gm * OUTW + gn[ni]] = gz * (acc[mi][ni][r] + bias[ni] - lz);
                }
            }
        }
    }
}

// ---------------------------------------------------------------- row reduce -> logZ
__global__ void __launch_bounds__(128) k_rowred(const float2* __restrict__ partials,
                                                float* __restrict__ logZs) {
    int row = blockIdx.x;
    int tid = threadIdx.x;
    float m = -__builtin_inff(), s = 0.f;
    for (int t = tid; t < NTILES; t += 128) {
        float2 p = partials[(size_t)row * NTILES + t];
        if (p.y > 0.f) {
            float nm = fmaxf(m, p.x);
            s = s * __expf(m - nm) + p.y * __expf(p.x - nm);
            m = nm;
        }
    }
    for (int o = 32; o; o >>= 1) {
        float om = __shfl_xor(m, o), os = __shfl_xor(s, o);
        float nm = fmaxf(m, om);
        s = s * __expf(m - nm) + os * __expf(om - nm);
        m = nm;
    }
    __shared__ float ms[2], ss[2];
    if ((tid & 63) == 0) { ms[tid >> 6] = m; ss[tid >> 6] = s; }
    __syncthreads();
    if (tid == 0) {
        float nm = fmaxf(ms[0], ms[1]);
        float S = ss[0] * __expf(ms[0] - nm) + ss[1] * __expf(ms[1] - nm);
        logZs[row] = nm + logf(S);
    }
}

// ----------------------------------------------------------------
extern "C" void kernel_launch(void* const* d_in, const int* in_sizes, int n_in,
                              void* d_out, int out_size, void* d_ws, size_t ws_size,
                              hipStream_t stream) {
    const int*   y      = (const int*)  d_in[0];
    const float* h1     = (const float*)d_in[1];
    const float* embed  = (const float*)d_in[2];
    const float* W_ih   = (const float*)d_in[3];
    const float* W_hh   = (const float*)d_in[4];
    const float* b_ih   = (const float*)d_in[5];
    const float* b_hh   = (const float*)d_in[6];
    const float* W_attn = (const float*)d_in[7];
    const float* b_attn = (const float*)d_in[8];
    const float* W_gate = (const float*)d_in[9];
    const float* b_gate = (const float*)d_in[10];
    const float* W_out  = (const float*)d_in[11];
    const float* b_out  = (const float*)d_in[12];
    float* out = (float*)d_out;

    char* wp = (char*)d_ws;
    auto alloc = [&](size_t bytes) {
        char* p = wp;
        wp += (bytes + 255) & ~(size_t)255;
        return p;
    };
    float* gi     = (float*)alloc((size_t)NROWS * G3 * 4);
    float* h2     = (float*)alloc((size_t)NROWS * HIDN * 4);
    float* wattnT = (float*)alloc((size_t)200 * 200 * 4);
    float* q      = (float*)alloc((size_t)NROWS * 200 * 4);
    float* kv     = (float*)alloc((size_t)BB * 200 * 200 * 4);
    float* gbuf   = (float*)alloc((size_t)NROWS * 4);
    float* logZs  = (float*)alloc((size_t)NROWS * 4);
    float2* partials      = (float2*)alloc((size_t)MP * NTILES * 8);
    unsigned short* s2b   = (unsigned short*)alloc((size_t)MP * KP * 2);
    unsigned short* woutT = (unsigned short*)alloc((size_t)NP * KP * 2);

    k_wattnT<<<dim3(157), dim3(256), 0, stream>>>(W_attn, wattnT);
    k_small_gemm<1><<<dim3(25, 19), dim3(256), 0, stream>>>(embed, W_ih, b_ih, gi, y, NROWS, G3);
    k_gru_wout<<<dim3(BB + WBLKS), dim3(512), 0, stream>>>(gi, W_hh, b_hh, h1, h2, W_out, woutT);
    k_small_gemm<0><<<dim3(25, 7),  dim3(256), 0, stream>>>(h2, wattnT, b_attn, q,  nullptr, NROWS, 200);
    k_small_gemm<2><<<dim3(100, 7), dim3(256), 0, stream>>>(h1, wattnT, b_attn, kv, nullptr, BB * 200, 200);
    k_attn<<<dim3(NROWS), dim3(256), 0, stream>>>(q, kv, h2, W_gate, b_gate, out, gbuf, s2b);
    k_gemm_big<<<dim3(MTILES, NTILES), dim3(256), 0, stream>>>(1, s2b, woutT, b_out, partials, logZs, gbuf, out);
    k_rowred<<<dim3(NROWS), dim3(128), 0, stream>>>(partials, logZs);
    k_gemm_big<<<dim3(MTILES, NTILES), dim3(256), 0, stream>>>(2, s2b, woutT, b_out, partials, logZs, gbuf, out);
}

// Round 11
// 676.390 us; speedup vs baseline: 1.6679x; 1.6679x over previous
//
#include <hip/hip_runtime.h>
#include <hip/hip_bf16.h>
#include <math.h>
#include <stdint.h>

#define DEVINL __device__ __forceinline__

constexpr int BB    = 16;
constexpr int TT    = 50;
constexpr int VV    = 50000;
constexpr int HIDN  = 200;
constexpr int G3    = 600;      // 3*HID
constexpr int NROWS = BB * TT;  // 800
constexpr int KP    = 416;      // K=400 padded to mult of 32
constexpr int MP    = 896;      // 800 padded to mult of 128
constexpr int NP    = 50048;    // 50000 padded to mult of 128
constexpr int NTILES = NP / 128; // 391
constexpr int MTILES = MP / 128; // 7
constexpr int OUTW  = VV + HIDN; // 50200
constexpr int WBLKS = NP / 64;   // 782 wout-transpose blocks

typedef __attribute__((ext_vector_type(4))) float f32x4;
typedef __attribute__((ext_vector_type(8))) short bf16x8;

DEVINL unsigned short f2bf(float v) {
    __hip_bfloat16 b = __float2bfloat16(v);
    return *reinterpret_cast<unsigned short*>(&b);
}
DEVINL float bflo(unsigned u) { return __uint_as_float(u << 16); }
DEVINL float bfhi(unsigned u) { return __uint_as_float(u & 0xffff0000u); }

DEVINL void gl_lds16(const void* g, void* lds) {
    __builtin_amdgcn_global_load_lds((const __attribute__((address_space(1))) void*)g,
                                     (__attribute__((address_space(3))) void*)lds,
                                     16, 0, 0);
}

// ---------------------------------------------------------------- W_attn^T
__global__ void __launch_bounds__(256) k_wattnT(const float* __restrict__ W,
                                                float* __restrict__ WT) {
    int i = blockIdx.x * 256 + threadIdx.x;
    if (i < 200 * 200) {
        int k = i / 200, n = i - k * 200;
        WT[(size_t)n * 200 + k] = W[i];
    }
}

// ------------------------------------------- small fp32 GEMM: C = A @ B^T + bias
template <int MODE>
__global__ void __launch_bounds__(256) k_small_gemm(const float* __restrict__ A,
                                                    const float* __restrict__ Brows,
                                                    const float* __restrict__ bias,
                                                    float* __restrict__ C,
                                                    const int* __restrict__ yidx,
                                                    int M, int N) {
    __shared__ float Ash[32][200];
    __shared__ float Bsh[32][200];
    int m0 = blockIdx.x * 32, n0 = blockIdx.y * 32;
    int tid = threadIdx.x;
    for (int i = tid; i < 32 * 200; i += 256) {
        int r = i / 200, k = i - r * 200;
        int gm = m0 + r;
        const float* src;
        if (MODE == 0)      src = A + (size_t)gm * 200;
        else if (MODE == 1) src = A + (size_t)yidx[gm] * 200;
        else { int bb = gm / 200, ss = gm - bb * 200; src = A + ((size_t)bb * 201 + ss) * 200; }
        Ash[r][k] = src[k];
    }
    for (int i = tid; i < 32 * 200; i += 256) {
        int r = i / 200, k = i - r * 200;
        int gn = n0 + r;
        Bsh[r][k] = (gn < N) ? Brows[(size_t)gn * 200 + k] : 0.f;
    }
    __syncthreads();
    int tx = tid & 15, ty = tid >> 4;
    float acc00 = 0, acc01 = 0, acc10 = 0, acc11 = 0;
    #pragma unroll 4
    for (int k = 0; k < 200; ++k) {
        float a0 = Ash[ty][k], a1 = Ash[ty + 16][k];
        float b0 = Bsh[tx][k], b1 = Bsh[tx + 16][k];
        acc00 += a0 * b0; acc01 += a0 * b1;
        acc10 += a1 * b0; acc11 += a1 * b1;
    }
    int gm0 = m0 + ty, gm1 = m0 + ty + 16;
    int gn0 = n0 + tx, gn1 = n0 + tx + 16;
    if (gn0 < N) { C[(size_t)gm0 * N + gn0] = acc00 + bias[gn0];
                   C[(size_t)gm1 * N + gn0] = acc10 + bias[gn0]; }
    if (gn1 < N) { C[(size_t)gm0 * N + gn1] = acc01 + bias[gn1];
                   C[(size_t)gm1 * N + gn1] = acc11 + bias[gn1]; }
}

// ---------------------------------------------------------------- fused GRU + W_out transpose
// LDS union: GRU 76 KB / wout tile 52.8 KB -> 2 blocks/CU at launch_bounds(512,2).
// Wout phase A: 5 batches x 5 independent float2 loads into regs (amortize HBM
// latency), then cvt + 4B LDS writes (conflict-free). Phase B = round-6 layout.
__global__ void __launch_bounds__(512, 2) k_gru_wout(const float* __restrict__ gi,
                                                     const float* __restrict__ W_hh,
                                                     const float* __restrict__ b_hh,
                                                     const float* __restrict__ h1,
                                                     float* __restrict__ h2,
                                                     const float* __restrict__ W_out,
                                                     unsigned short* __restrict__ WT) {
    __shared__ __align__(16) char smem[76000];
    const int t = threadIdx.x;

    if (blockIdx.x >= BB) {
        // ---------------- W_out transpose: [400][VV] f32 -> [NP][KP] bf16
        unsigned short (*tile)[66] = reinterpret_cast<unsigned short(*)[66]>(smem); // 52.8 KB
        const int n0 = (blockIdx.x - BB) * 64;
        const bool full = (n0 + 64 <= VV);
        // 400 rows x 32 float2-cols = 12800 items; item i: k=i>>5, c=i&31
        float2 regs[5];
        #pragma unroll
        for (int batch = 0; batch < 5; ++batch) {
            #pragma unroll
            for (int u = 0; u < 5; ++u) {            // issue 5 independent loads
                int i = t + (batch * 5 + u) * 512;
                int k = i >> 5, c = i & 31;
                int gn = n0 + c * 2;
                const float* src = W_out + (size_t)k * VV + gn;
                if (full) {
                    regs[u] = *reinterpret_cast<const float2*>(src);
                } else {
                    float2 v;
                    v.x = (gn     < VV) ? src[0] : 0.f;
                    v.y = (gn + 1 < VV) ? src[1] : 0.f;
                    regs[u] = v;
                }
            }
            #pragma unroll
            for (int u = 0; u < 5; ++u) {            // then consume
                int i = t + (batch * 5 + u) * 512;
                int k = i >> 5, c = i & 31;
                unsigned p = (unsigned)f2bf(regs[u].x) | ((unsigned)f2bf(regs[u].y) << 16);
                *reinterpret_cast<unsigned*>(&tile[k][c * 2]) = p;
            }
        }
        __syncthreads();
        // 64 rows x 208 dwords, consecutive lanes -> consecutive dwords (round-6)
        for (int i = t; i < 64 * 208; i += 512) {
            int n = i / 208, dw = i - n * 208;
            int k = dw * 2;
            unsigned int lo = (k < 400) ? (unsigned int)tile[k][n] : 0u;
            unsigned int hi = (k + 1 < 400) ? (unsigned int)tile[k + 1][n] : 0u;
            reinterpret_cast<unsigned int*>(WT + (size_t)(n0 + n) * KP)[dw] = lo | (hi << 16);
        }
        return;
    }

    // ---------------- GRU path (identical math to round 6) ----------------
    float (*wlds)[200] = reinterpret_cast<float(*)[200]>(smem);          // 70400 B
    float* hsh = reinterpret_cast<float*>(smem + 70400);                 // 800 B
    float* pre = reinterpret_cast<float*>(smem + 71200);                 // 2400 B
    float* bsh = reinterpret_cast<float*>(smem + 73600);                 // 2400 B
    const int b = blockIdx.x;

    uint4 wb[25];   // W_hh row t as packed bf16 (100 VGPR, static indexing)
    {
        const float4* wrow = reinterpret_cast<const float4*>(W_hh + (size_t)t * 200);
        #pragma unroll
        for (int i = 0; i < 25; ++i) {
            float4 a = wrow[2 * i], c = wrow[2 * i + 1];
            wb[i].x = (unsigned)f2bf(a.x) | ((unsigned)f2bf(a.y) << 16);
            wb[i].y = (unsigned)f2bf(a.z) | ((unsigned)f2bf(a.w) << 16);
            wb[i].z = (unsigned)f2bf(c.x) | ((unsigned)f2bf(c.y) << 16);
            wb[i].w = (unsigned)f2bf(c.z) | ((unsigned)f2bf(c.w) << 16);
        }
    }
    for (int i = t; i < 88 * 200; i += 512) {
        int r = i / 200, k = i - r * 200;
        wlds[r][k] = W_hh[(size_t)(512 + r) * 200 + k];
    }
    for (int i = t; i < 600; i += 512) bsh[i] = b_hh[i];
    if (t < 200) hsh[t] = h1[((size_t)b * 201 + 200) * 200 + t];
    __syncthreads();

    const float4* hsh4 = reinterpret_cast<const float4*>(hsh);
    const int lr = t >> 1, lq = t & 1;

    for (int step = 0; step < TT; ++step) {
        float gr = 0.f, gz = 0.f, gn_ = 0.f, hold = 0.f;
        if (t < 200) {
            const float* girow = gi + ((size_t)b * TT + step) * G3 + t;
            gr  = girow[0];
            gz  = girow[200];
            gn_ = girow[400];
            hold = hsh[t];
        }

        float a0 = 0.f, a1 = 0.f, a2 = 0.f, a3 = 0.f;
        #pragma unroll
        for (int i = 0; i < 25; ++i) {
            uint4 w = wb[i];
            float4 h0 = hsh4[2 * i], h1v = hsh4[2 * i + 1];
            a0 += bflo(w.x) * h0.x;  a1 += bfhi(w.x) * h0.y;
            a2 += bflo(w.y) * h0.z;  a3 += bfhi(w.y) * h0.w;
            a0 += bflo(w.z) * h1v.x; a1 += bfhi(w.z) * h1v.y;
            a2 += bflo(w.w) * h1v.z; a3 += bfhi(w.w) * h1v.w;
        }
        pre[t] = (a0 + a1) + (a2 + a3);

        if (t < 176) {
            const float4* wr4 = reinterpret_cast<const float4*>(&wlds[lr][lq * 100]);
            const float4* hh4 = hsh4 + lq * 25;
            float c0 = 0.f, c1 = 0.f, c2 = 0.f, c3 = 0.f;
            #pragma unroll
            for (int i = 0; i < 25; ++i) {
                float4 wvv = wr4[i];
                float4 hv  = hh4[i];
                c0 += wvv.x * hv.x;
                c1 += wvv.y * hv.y;
                c2 += wvv.z * hv.z;
                c3 += wvv.w * hv.w;
            }
            float cc = (c0 + c1) + (c2 + c3);
            cc += __shfl_xor(cc, 1);
            if (lq == 0) pre[512 + lr] = cc;
        }
        __syncthreads();

        if (t < 200) {
            float pr = gr  + pre[t]       + bsh[t];
            float pz = gz  + pre[200 + t] + bsh[200 + t];
            float hn = pre[400 + t] + bsh[400 + t];
            float r = 1.f / (1.f + __expf(-pr));
            float z = 1.f / (1.f + __expf(-pz));
            float n = tanhf(gn_ + r * hn);
            float hnew = (1.f - z) * n + z * hold;
            hsh[t] = hnew;
            h2[((size_t)b * TT + step) * 200 + t] = hnew;
        }
        __syncthreads();
    }
}

// ---------------------------------------------------------------- fused attention + gate
__global__ void __launch_bounds__(256) k_attn(const float* __restrict__ q,
                                              const float* __restrict__ kv,
                                              const float* __restrict__ h2,
                                              const float* __restrict__ W_gate,
                                              const float* __restrict__ b_gate,
                                              float* __restrict__ out,
                                              float* __restrict__ gbuf,
                                              unsigned short* __restrict__ s2b) {
    int row = blockIdx.x;
    int b = row / TT;
    int tid = threadIdx.x;
    __shared__ __align__(16) float qsh[200];
    __shared__ __align__(16) float h2sh[200];
    __shared__ float ash[200];
    __shared__ float csh[200];
    __shared__ float red[8];

    if (tid < 50) {
        reinterpret_cast<float4*>(qsh)[tid]  = reinterpret_cast<const float4*>(q  + (size_t)row * 200)[tid];
        reinterpret_cast<float4*>(h2sh)[tid] = reinterpret_cast<const float4*>(h2 + (size_t)row * 200)[tid];
    }
    __syncthreads();

    const float* kvb = kv + (size_t)b * 200 * 200;
    float dval = -__builtin_inff();
    if (tid < 200) {
        const float4* kr = reinterpret_cast<const float4*>(kvb + (size_t)tid * 200);
        float s = 0.f;
        #pragma unroll 5
        for (int k4 = 0; k4 < 50; ++k4) {
            float4 kvv = kr[k4];
            float4 qv = reinterpret_cast<float4*>(qsh)[k4];
            s += kvv.x * qv.x + kvv.y * qv.y + kvv.z * qv.z + kvv.w * qv.w;
        }
        dval = s * 0.07071067811865475f;  // 1/sqrt(200)
    }
    float m = dval;
    for (int o = 32; o; o >>= 1) m = fmaxf(m, __shfl_xor(m, o));
    if ((tid & 63) == 0) red[tid >> 6] = m;
    __syncthreads();
    m = fmaxf(fmaxf(red[0], red[1]), fmaxf(red[2], red[3]));
    float e = (tid < 200) ? __expf(dval - m) : 0.f;
    float ssum = e;
    for (int o = 32; o; o >>= 1) ssum += __shfl_xor(ssum, o);
    if ((tid & 63) == 0) red[4 + (tid >> 6)] = ssum;
    __syncthreads();
    float Ssum = red[4] + red[5] + red[6] + red[7];
    float logS = logf(Ssum);
    float p1v = dval - m - logS;
    if (tid < 200) ash[tid] = e / Ssum;
    __syncthreads();

    if (tid < 200) {
        float c = 0.f;
        #pragma unroll 4
        for (int s = 0; s < 200; ++s) c += ash[s] * kvb[(size_t)s * 200 + tid];
        csh[tid] = c;
    }
    __syncthreads();

    float gv = 0.f;
    if (tid < 200) gv = h2sh[tid] * W_gate[tid] + csh[tid] * W_gate[200 + tid];
    for (int o = 32; o; o >>= 1) gv += __shfl_xor(gv, o);
    if ((tid & 63) == 0) red[tid >> 6] = gv;
    __syncthreads();
    float g = red[0] + red[1] + red[2] + red[3] + b_gate[0];

    if (tid == 0) gbuf[row] = g;
    if (tid < 200) out[(size_t)row * OUTW + VV + tid] = (1.f - g) * p1v;

    if (tid < 208) {
        int k = tid * 2;
        float v0 = (k < 200) ? h2sh[k] : (k < 400) ? csh[k - 200] : 0.f;
        float v1 = (k + 1 < 200) ? h2sh[k + 1] : (k + 1 < 400) ? csh[k + 1 - 200] : 0.f;
        unsigned int pk = (unsigned int)f2bf(v0) | ((unsigned int)f2bf(v1) << 16);
        reinterpret_cast<unsigned int*>(s2b + (size_t)row * KP)[tid] = pk;
    }
}

// ---------------------------------------------------------------- big bf16 MFMA GEMM
__global__ void __launch_bounds__(256) k_gemm_big(int pass,
        const unsigned short* __restrict__ Ab, const unsigned short* __restrict__ Bb,
        const float* __restrict__ b_out, float2* __restrict__ partials,
        const float* __restrict__ logZs, const float* __restrict__ gbuf,
        float* __restrict__ out) {
    __shared__ __align__(16) unsigned short Ash[128 * 32];
    __shared__ __align__(16) unsigned short Bsh[128 * 32];
    __shared__ float redsh[128][2][2];
    __shared__ float zsh[128], gsh[128];

    const int m0 = blockIdx.x * 128, n0 = blockIdx.y * 128;
    const int tid = threadIdx.x;
    const int lane = tid & 63, wid = tid >> 6;
    const int wr = wid >> 1, wc = wid & 1;
    const int rq = lane >> 4, r15 = lane & 15;

    if (pass == 2 && tid < 128) {
        int gm = m0 + tid;
        zsh[tid] = (gm < NROWS) ? logZs[gm] : 0.f;
        gsh[tid] = (gm < NROWS) ? gbuf[gm] : 0.f;
    }

    const int c2 = tid + 256;
    const unsigned short* a1 = Ab + (size_t)(m0 + (tid >> 2)) * KP + (tid & 3) * 8;
    const unsigned short* a2 = Ab + (size_t)(m0 + (c2 >> 2)) * KP + (c2 & 3) * 8;
    const unsigned short* b1 = Bb + (size_t)(n0 + (tid >> 2)) * KP + (tid & 3) * 8;
    const unsigned short* b2 = Bb + (size_t)(n0 + (c2 >> 2)) * KP + (c2 & 3) * 8;
    unsigned short* ldsA1 = Ash + wid * 512;
    unsigned short* ldsA2 = Ash + wid * 512 + 2048;
    unsigned short* ldsB1 = Bsh + wid * 512;
    unsigned short* ldsB2 = Bsh + wid * 512 + 2048;

    f32x4 zero = {0.f, 0.f, 0.f, 0.f};
    f32x4 acc[4][4];
    #pragma unroll
    for (int i = 0; i < 4; ++i)
        #pragma unroll
        for (int j = 0; j < 4; ++j) acc[i][j] = zero;

    const bf16x8* A8 = reinterpret_cast<const bf16x8*>(Ash);
    const bf16x8* B8 = reinterpret_cast<const bf16x8*>(Bsh);

    for (int kt = 0; kt < KP / 32; ++kt) {
        const int ko = kt * 32;
        gl_lds16(a1 + ko, ldsA1);
        gl_lds16(a2 + ko, ldsA2);
        gl_lds16(b1 + ko, ldsB1);
        gl_lds16(b2 + ko, ldsB2);
        __syncthreads();
        bf16x8 af[4], bfr[4];
        #pragma unroll
        for (int mi = 0; mi < 4; ++mi) af[mi] = A8[(wr * 64 + mi * 16 + r15) * 4 + rq];
        #pragma unroll
        for (int ni = 0; ni < 4; ++ni) bfr[ni] = B8[(wc * 64 + ni * 16 + r15) * 4 + rq];
        #pragma unroll
        for (int mi = 0; mi < 4; ++mi)
            #pragma unroll
            for (int ni = 0; ni < 4; ++ni)
                acc[mi][ni] = __builtin_amdgcn_mfma_f32_16x16x32_bf16(af[mi], bfr[ni], acc[mi][ni], 0, 0, 0);
        __syncthreads();
    }

    float bias[4]; bool nok[4]; int gn[4];
    #pragma unroll
    for (int ni = 0; ni < 4; ++ni) {
        gn[ni] = n0 + wc * 64 + ni * 16 + r15;
        nok[ni] = gn[ni] < VV;
        bias[ni] = nok[ni] ? b_out[gn[ni]] : 0.f;
    }

    if (pass == 1) {
        #pragma unroll
        for (int mi = 0; mi < 4; ++mi) {
            #pragma unroll
            for (int r = 0; r < 4; ++r) {
                float v[4]; float mx = -__builtin_inff();
                #pragma unroll
                for (int ni = 0; ni < 4; ++ni) {
                    v[ni] = nok[ni] ? (acc[mi][ni][r] + bias[ni]) : -__builtin_inff();
                    mx = fmaxf(mx, v[ni]);
                }
                #pragma unroll
                for (int o = 1; o < 16; o <<= 1) mx = fmaxf(mx, __shfl_xor(mx, o));
                float se = 0.f;
                #pragma unroll
                for (int ni = 0; ni < 4; ++ni) se += nok[ni] ? __expf(v[ni] - mx) : 0.f;
                #pragma unroll
                for (int o = 1; o < 16; o <<= 1) se += __shfl_xor(se, o);
                int ml = wr * 64 + mi * 16 + rq * 4 + r;
                if (r15 == 0) { redsh[ml][wc][0] = mx; redsh[ml][wc][1] = se; }
            }
        }
        __syncthreads();
        if (tid < 128) {
            float m1 = redsh[tid][0][0], s1 = redsh[tid][0][1];
            float m2 = redsh[tid][1][0], s2 = redsh[tid][1][1];
            float mm = fmaxf(m1, m2);
            float ss = s1 * __expf(m1 - mm) + s2 * __expf(m2 - mm);
            partials[(size_t)(m0 + tid) * NTILES + blockIdx.y] = float2{mm, ss};
        }
    } else {
        #pragma unroll
        for (int mi = 0; mi < 4; ++mi) {
            #pragma unroll
            for (int r = 0; r < 4; ++r) {
                int ml = wr * 64 + mi * 16 + rq * 4 + r;
                int gm = m0 + ml;
                if (gm < NROWS) {
                    float gz = gsh[ml], lz = zsh[ml];
                    #pragma unroll
                    for (int ni = 0; ni < 4; ++ni)
                        if (nok[ni])
                            out[(size_t)gm * OUTW + gn[ni]] = gz * (acc[mi][ni][r] + bias[ni] - lz);
                }
            }
        }
    }
}

// ---------------------------------------------------------------- row reduce -> logZ
__global__ void __launch_bounds__(128) k_rowred(const float2* __restrict__ partials,
                                                float* __restrict__ logZs) {
    int row = blockIdx.x;
    int tid = threadIdx.x;
    float m = -__builtin_inff(), s = 0.f;
    for (int t = tid; t < NTILES; t += 128) {
        float2 p = partials[(size_t)row * NTILES + t];
        if (p.y > 0.f) {
            float nm = fmaxf(m, p.x);
            s = s * __expf(m - nm) + p.y * __expf(p.x - nm);
            m = nm;
        }
    }
    for (int o = 32; o; o >>= 1) {
        float om = __shfl_xor(m, o), os = __shfl_xor(s, o);
        float nm = fmaxf(m, om);
        s = s * __expf(m - nm) + os * __expf(om - nm);
        m = nm;
    }
    __shared__ float ms[2], ss[2];
    if ((tid & 63) == 0) { ms[tid >> 6] = m; ss[tid >> 6] = s; }
    __syncthreads();
    if (tid == 0) {
        float nm = fmaxf(ms[0], ms[1]);
        float S = ss[0] * __expf(ms[0] - nm) + ss[1] * __expf(ms[1] - nm);
        logZs[row] = nm + logf(S);
    }
}

// ----------------------------------------------------------------
extern "C" void kernel_launch(void* const* d_in, const int* in_sizes, int n_in,
                              void* d_out, int out_size, void* d_ws, size_t ws_size,
                              hipStream_t stream) {
    const int*   y      = (const int*)  d_in[0];
    const float* h1     = (const float*)d_in[1];
    const float* embed  = (const float*)d_in[2];
    const float* W_ih   = (const float*)d_in[3];
    const float* W_hh   = (const float*)d_in[4];
    const float* b_ih   = (const float*)d_in[5];
    const float* b_hh   = (const float*)d_in[6];
    const float* W_attn = (const float*)d_in[7];
    const float* b_attn = (const float*)d_in[8];
    const float* W_gate = (const float*)d_in[9];
    const float* b_gate = (const float*)d_in[10];
    const float* W_out  = (const float*)d_in[11];
    const float* b_out  = (const float*)d_in[12];
    float* out = (float*)d_out;

    char* wp = (char*)d_ws;
    auto alloc = [&](size_t bytes) {
        char* p = wp;
        wp += (bytes + 255) & ~(size_t)255;
        return p;
    };
    float* gi     = (float*)alloc((size_t)NROWS * G3 * 4);
    float* h2     = (float*)alloc((size_t)NROWS * HIDN * 4);
    float* wattnT = (float*)alloc((size_t)200 * 200 * 4);
    float* q      = (float*)alloc((size_t)NROWS * 200 * 4);
    float* kv     = (float*)alloc((size_t)BB * 200 * 200 * 4);
    float* gbuf   = (float*)alloc((size_t)NROWS * 4);
    float* logZs  = (float*)alloc((size_t)NROWS * 4);
    float2* partials      = (float2*)alloc((size_t)MP * NTILES * 8);
    unsigned short* s2b   = (unsigned short*)alloc((size_t)MP * KP * 2);
    unsigned short* woutT = (unsigned short*)alloc((size_t)NP * KP * 2);

    k_wattnT<<<dim3(157), dim3(256), 0, stream>>>(W_attn, wattnT);
    k_small_gemm<1><<<dim3(25, 19), dim3(256), 0, stream>>>(embed, W_ih, b_ih, gi, y, NROWS, G3);
    k_gru_wout<<<dim3(BB + WBLKS), dim3(512), 0, stream>>>(gi, W_hh, b_hh, h1, h2, W_out, woutT);
    k_small_gemm<0><<<dim3(25, 7),  dim3(256), 0, stream>>>(h2, wattnT, b_attn, q,  nullptr, NROWS, 200);
    k_small_gemm<2><<<dim3(100, 7), dim3(256), 0, stream>>>(h1, wattnT, b_attn, kv, nullptr, BB * 200, 200);
    k_attn<<<dim3(NROWS), dim3(256), 0, stream>>>(q, kv, h2, W_gate, b_gate, out, gbuf, s2b);
    k_gemm_big<<<dim3(MTILES, NTILES), dim3(256), 0, stream>>>(1, s2b, woutT, b_out, partials, logZs, gbuf, out);
    k_rowred<<<dim3(NROWS), dim3(128), 0, stream>>>(partials, logZs);
    k_gemm_big<<<dim3(MTILES, NTILES), dim3(256), 0, stream>>>(2, s2b, woutT, b_out, partials, logZs, gbuf, out);
}